// Round 15
// baseline (628.272 us; speedup 1.0000x reference)
//
#include <hip/hip_runtime.h>
#include <stdint.h>

#define S   128
#define NB  32
#define NC  256
#define DK  128
#define NSL 4
#define HROW 264   // hsb row stride bytes: 264=8*33 -> bank stagger, 2-way max on b64

typedef __bf16 bf16x8 __attribute__((ext_vector_type(8)));
typedef float  f32x16 __attribute__((ext_vector_type(16)));
typedef unsigned int u32x4 __attribute__((ext_vector_type(4)));
typedef unsigned int u32x2 __attribute__((ext_vector_type(2)));
typedef _Float16 f16x2 __attribute__((ext_vector_type(2)));
static_assert(sizeof(bf16x8) == 16, "bf16x8 size");
static_assert(sizeof(f16x2) == 4, "f16x2 size");

// d_ws layout (float offsets).
#define OFF_AL   0            // AL; later OFF_HT (reduced h_tilde) reuse
#define OFF_HT   OFF_AL
#define OFF_P2   524288
#define OFF_P3   1044480
#define OFF_PS   1564672
#define OFF_PY   2084864
#define OFF_CM   2670592      // u32 comm [32 b][2 slot][8 pub][128 j] = 1MB (memset 0 each launch)

__device__ __forceinline__ float v_exp2(float x){ float r; asm("v_exp_f32 %0, %1" : "=v"(r) : "v"(x)); return r; }
__device__ __forceinline__ float v_rcp (float x){ float r; asm("v_rcp_f32 %0, %1" : "=v"(r) : "v"(x)); return r; }
__device__ __forceinline__ float sigm(float x){ return v_rcp(1.0f + v_exp2(x * -1.4426950408889634f)); }
__device__ __forceinline__ uint32_t pkbf(float lo, float hi){
  uint32_t r; asm("v_cvt_pk_bf16_f32 %0, %1, %2" : "=v"(r) : "v"(lo), "v"(hi)); return r;
}
__device__ __forceinline__ float bfhi(uint32_t w){ return __builtin_bit_cast(float, w & 0xffff0000u); }
__device__ __forceinline__ uint32_t pkh(float a, float b){
  return __builtin_bit_cast(uint32_t, __builtin_amdgcn_cvt_pkrtz(a, b));
}
__device__ __forceinline__ float fdot2u(uint32_t a, uint32_t b, float c){
  return __builtin_amdgcn_fdot2(__builtin_bit_cast(f16x2, a), __builtin_bit_cast(f16x2, b), c, false);
}
// LDS-only barrier (no vmcnt drain): publish/HT stores and prefetch loads stay in flight.
__device__ __forceinline__ void barrier_lgkm(){
  asm volatile("s_waitcnt lgkmcnt(0)" ::: "memory");
  __builtin_amdgcn_s_barrier();
}
#define NLOG2E (-1.4426950408889634f)

// ---------------- kernel 0: AL = concat(e_emb, at_emb, a*ones50) @ W1 + b1 ----------------
__global__ __launch_bounds__(512) void k0_al(
    const int* __restrict__ e_data, const int* __restrict__ at_data,
    const float* __restrict__ a_data, const float* __restrict__ e_E,
    const float* __restrict__ at_E, const float* __restrict__ W1,
    const float* __restrict__ b1, float* __restrict__ ws)
{
  __shared__ float ein[32][128];
  __shared__ float atin[32][128];
  int b = blockIdx.x >> 2, q4 = blockIdx.x & 3, t0 = q4 * 32;
  for (int idx = threadIdx.x; idx < 32 * 128; idx += 512) {
    int r = idx >> 7, j = idx & 127;
    int ev  = e_data [b * S + t0 + r];
    int atv = at_data[b * S + t0 + r];
    ein [r][j] = e_E [ev  * DK + j];
    atin[r][j] = at_E[atv * DK + j];
  }
  __syncthreads();
  int j = threadIdx.x & 127, tq = threadIdx.x >> 7;
  float w1s = 0.f;
  for (int d = 0; d < 50; ++d) w1s += W1[(256 + d) * DK + j];
  float acc[8];
#pragma unroll
  for (int u = 0; u < 8; ++u) {
    int t = t0 + tq * 8 + u;
    acc[u] = b1[j] + a_data[b * S + t] * w1s;
  }
  for (int k = 0; k < 128; ++k) {
    float w = W1[k * DK + j];
#pragma unroll
    for (int u = 0; u < 8; ++u) acc[u] += ein[tq * 8 + u][k] * w;
  }
  for (int k = 0; k < 128; ++k) {
    float w = W1[(128 + k) * DK + j];
#pragma unroll
    for (int u = 0; u < 8; ++u) acc[u] += atin[tq * 8 + u][k] * w;
  }
#pragma unroll
  for (int u = 0; u < 8; ++u)
    ws[OFF_AL + (b * S + t0 + tq * 8 + u) * DK + j] = acc[u];
}

// ---------------- kernel 1: carry-independent per-step preactivations ----------------
__global__ __launch_bounds__(512) void k1_pre(
    const int* __restrict__ e_data, const int* __restrict__ it_data,
    const float* __restrict__ it_E, const float* __restrict__ e_E,
    const float* __restrict__ W2, const float* __restrict__ b2,
    const float* __restrict__ W3, const float* __restrict__ b3,
    const float* __restrict__ W4, const float* __restrict__ b4,
    const float* __restrict__ W5, const float* __restrict__ b5,
    float* __restrict__ ws)
{
  __shared__ float als[33][128];
  __shared__ float its[32][128];
  __shared__ float ens[32][128];
  int b = blockIdx.x >> 2, sh = blockIdx.x & 3, s0 = sh * 32;
  for (int idx = threadIdx.x; idx < 33 * 128; idx += 512) {
    int r = idx >> 7, j = idx & 127;
    int srow = s0 - 1 + r;
    als[r][j] = (srow >= 0) ? ws[OFF_AL + (b * S + srow) * DK + j] : 0.f;
  }
  for (int idx = threadIdx.x; idx < 32 * 128; idx += 512) {
    int r = idx >> 7, j = idx & 127;
    int itv = it_data[b * S + s0 + r];
    its[r][j] = it_E[itv * DK + j];
    int sg = s0 + r + 1; if (sg > 127) sg = 127;
    int ev = e_data[b * S + sg];
    ens[r][j] = e_E[ev * DK + j];
  }
  __syncthreads();
  int j = threadIdx.x & 127, sq = threadIdx.x >> 7;
  float p2[8], p3[8], pS[8], pY[8];
#pragma unroll
  for (int u = 0; u < 8; ++u) { p2[u] = b2[j]; p3[u] = b3[j]; pS[u] = b4[j]; pY[u] = b5[j]; }
  for (int k = 0; k < 128; ++k) {
    float w2 = W2[k * DK + j], w3 = W3[k * DK + j];
#pragma unroll
    for (int u = 0; u < 8; ++u) { float v = als[sq * 8 + u][k]; p2[u] += v * w2; p3[u] += v * w3; }
  }
  for (int k = 0; k < 128; ++k) {
    float w2 = W2[(128 + k) * DK + j], w3 = W3[(128 + k) * DK + j], w4 = W4[(256 + k) * DK + j];
#pragma unroll
    for (int u = 0; u < 8; ++u) { float v = its[sq * 8 + u][k]; p2[u] += v * w2; p3[u] += v * w3; pS[u] += v * w4; }
  }
  for (int k = 0; k < 128; ++k) {
    float w2 = W2[(256 + k) * DK + j], w3 = W3[(256 + k) * DK + j];
#pragma unroll
    for (int u = 0; u < 8; ++u) { float v = als[sq * 8 + u + 1][k]; p2[u] += v * w2; p3[u] += v * w3; }
  }
  for (int k = 0; k < 128; ++k) {
    float w5 = W5[k * DK + j];
#pragma unroll
    for (int u = 0; u < 8; ++u) pY[u] += ens[sq * 8 + u][k] * w5;
  }
#pragma unroll
  for (int u = 0; u < 8; ++u) {
    int s = s0 + sq * 8 + u;
    if (s < 127) {
      int o = (b * 127 + s) * DK + j;
      ws[OFF_P2 + o] = p2[u]; ws[OFF_P3 + o] = p3[u];
      ws[OFF_PS + o] = pS[u]; ws[OFF_PY + o] = pY[u];
    }
  }
}

// ---------------- main recurrent kernel: DUAL-ROW blocks, 4 CUs/row-pair ----------------
// grid 64 = slice(0..3) x bpair(0..15); block carries rows b0=2bp, b1=2bp+1 through the
// R13 3-phase schedule. Per step:
//  P1 [prefetch issue (both rows); MFMA r0 -> acc0; MFMA r1 -> acc1; gathers: waves 0/1
//      row0 halves, waves 2/3 row1 halves (tagged u32, retry)] bA
//  P2 [HT stores (slice0: wv<2 row0, wv2/3 row1); A-dot r0 -> LGp[0]; A-dot r1 -> LGp[1]] bB
//  X  [commit prefetch; {B-dot, gamma/update, hsb write, publish} r0 then r1] bD
// The two rows' chains are independent: row1 compute fills row0's stall slots.
// Weights shared (Awh regs, W4B/W4Lh LDS). Exchange protocol per row unchanged.
__global__ __launch_bounds__(512, 2) void kmain(
    const int* __restrict__ e_data, const float* __restrict__ qmat,
    const float* __restrict__ W2, const float* __restrict__ W3,
    const float* __restrict__ W4, const float* __restrict__ h0,
    float* ws)
{
  __shared__ char     hsb[2][64 * HROW];  // h slices bf16, staggered rows (33.8KB)
  __shared__ u32x4    W4B[4][8][64];      // W4[0:128] MFMA B-frags per jt (32KB)
  __shared__ uint32_t W4Lh[64][128];      // W4[128:256] f16 pairs [k/2][j] (32KB)
  __shared__ float    qbuf[2][3][64];
  __shared__ float    PST[2][2][3][128];  // [row][par][m][j]
  __shared__ uint32_t htldp[2][64];
  __shared__ uint32_t LGp[2][64];

  const int bx = blockIdx.x;
  const int bp = bx & 15, slice = bx >> 4;
  const int tid = threadIdx.x;
  const int lane = tid & 63, wv = tid >> 6;
  const int ct = wv >> 2, jt = wv & 3;
  const int lo = lane & 31, hi = lane >> 5;
  const int jA = tid >> 2, am = (tid >> 1) & 1, akh = tid & 1;
  const int jloc = jt * 32 + lo;
  const int b0 = bp * 2, b1 = bp * 2 + 1;

  uint32_t* cm0 = (uint32_t*)(ws + OFF_CM) + (size_t)b0 * 2048;   // [slot][pub8][128]
  uint32_t* cm1 = (uint32_t*)(ws + OFF_CM) + (size_t)b1 * 2048;

  // ---- persistent registers: Awh (32 f16-pairs, shared) + hm[2][16] ----
  uint32_t Awh[32];
  {
    const float* Wm = am ? W3 : W2;
#pragma unroll
    for (int i = 0; i < 32; ++i) {
      float w0 = Wm[(384 + akh * 64 + 2 * i) * DK + jA];
      float w1 = Wm[(384 + akh * 64 + 2 * i + 1) * DK + jA];
      Awh[i] = pkh(w0, w1);
    }
  }
  float hm[2][16];
#pragma unroll
  for (int r = 0; r < 16; ++r) {
    int cl = ct * 32 + (r & 3) + 8 * (r >> 2) + 4 * hi;
    float v = h0[(slice * 64 + cl) * DK + jloc];     // h0 broadcast over batch
    hm[0][r] = v; hm[1][r] = v;
  }

  // ---- prologue LDS fills ----
  {
    uint32_t* w4b = (uint32_t*)&W4B[0][0][0];
#pragma unroll
    for (int it = 0; it < 16; ++it) {            // MFMA B-frags (bf16 pairs, frag layout)
      int idx = tid + it * 512;
      int w = idx & 3, l = (idx >> 2) & 63, kk = (idx >> 8) & 7, jb = idx >> 11;
      int llo = l & 31, lhi = l >> 5;
      int row = kk * 16 + lhi * 8 + 2 * w, col = jb * 32 + llo;
      w4b[idx] = pkbf(W4[row * DK + col], W4[(row + 1) * DK + col]);
    }
  }
#pragma unroll
  for (int it = 0; it < 16; ++it) {              // W4Lh: f16 pairs of W4 rows 128..255
    int idx = tid + it * 512, kp = idx >> 7, jj = idx & 127;
    W4Lh[kp][jj] = pkh(W4[(128 + 2 * kp) * DK + jj], W4[(128 + 2 * kp + 1) * DK + jj]);
  }
  if (tid < 128) {                               // q rows 0,1 for both batch rows
    int rr = tid >> 6, t6 = tid & 63;
    int bb = rr ? b1 : b0;
    qbuf[rr][0][t6] = qmat[e_data[bb * S + 0] * NC + slice * 64 + t6];
    qbuf[rr][1][t6] = qmat[e_data[bb * S + 1] * NC + slice * 64 + t6];
  }
  if (tid < 384) {                               // preacts row 0 for both batch rows
    int mm = tid >> 7, jj = tid & 127;
    int off = (mm == 0) ? OFF_P2 : (mm == 1) ? OFF_P3 : OFF_PS;
    PST[0][0][mm][jj] = ws[off + (b0 * 127 + 0) * DK + jj];
    PST[1][0][mm][jj] = ws[off + (b1 * 127 + 0) * DK + jj];
  }
#pragma unroll
  for (int r = 0; r < 16; ++r) {                 // pack h0 into both hsb
    int cl = ct * 32 + (r & 3) + 8 * (r >> 2) + 4 * hi;
    uint16_t v = (uint16_t)pkbf(hm[0][r], 0.f);
    *(uint16_t*)(&hsb[0][0] + cl * HROW + jloc * 2) = v;
    *(uint16_t*)(&hsb[1][0] + cl * HROW + jloc * 2) = v;
  }
  __syncthreads();

  // ---- prologue: publish h_tilde(0) partials (tag 1, slot 1), both rows ----
#pragma unroll
  for (int rr = 0; rr < 2; ++rr) {
    float ht = 0.f;
#pragma unroll
    for (int r = 0; r < 16; ++r) {
      int cl = ct * 32 + (r & 3) + 8 * (r >> 2) + 4 * hi;
      ht += qbuf[rr][0][cl] * hm[rr][r];
    }
    ht += __shfl_xor(ht, 32);
    uint32_t* cm = rr ? cm1 : cm0;
    if (hi == 0)
      __hip_atomic_store(&cm[1 * 1024 + (slice * 2 + ct) * 128 + jloc],
                         pkbf(0.f, ht) | 1u, __ATOMIC_RELAXED, __HIP_MEMORY_SCOPE_AGENT);
  }

  float vreg = 0.f;   // waves 0-3: gathered f32 h_tilde half (wv>>1 = row, wv&1 = half)

#pragma unroll 1
  for (int s = 0; s < S - 1; ++s) {
    const int par = s & 1;

    // ===== P1: prefetch issue + MFMA both rows + gathers (waves 0-3) =====
    float qld[2] = {0.f, 0.f}, pld[2] = {0.f, 0.f};
    if (tid >= 448) {
      int t6 = tid - 448;
      qld[0] = qmat[e_data[b0 * S + min(s + 2, S - 1)] * NC + slice * 64 + t6];
      qld[1] = qmat[e_data[b1 * S + min(s + 2, S - 1)] * NC + slice * 64 + t6];
    }
    if (tid >= 128) {
      int mm = (tid - 128) >> 7, jj = tid & 127;
      int off = (mm == 0) ? OFF_P2 : (mm == 1) ? OFF_P3 : OFF_PS;
      pld[0] = ws[off + (b0 * 127 + min(s + 1, 126)) * DK + jj];
      pld[1] = ws[off + (b1 * 127 + min(s + 1, 126)) * DK + jj];
    }

    f32x16 acc0, acc1;
#pragma unroll
    for (int r = 0; r < 16; ++r) { acc0[r] = 0.f; acc1[r] = 0.f; }
    {
      const int rowoff = (ct * 32 + lo) * HROW;
#pragma unroll
      for (int kk = 0; kk < 8; ++kk) {
        u32x4 bfr = W4B[jt][kk][lane];
        {
          const char* base = &hsb[0][0] + rowoff;
          u32x2 a0 = *(const u32x2*)(base + kk * 32 + hi * 16);
          u32x2 a1 = *(const u32x2*)(base + kk * 32 + hi * 16 + 8);
          u32x4 af4; af4[0] = a0[0]; af4[1] = a0[1]; af4[2] = a1[0]; af4[3] = a1[1];
          acc0 = __builtin_amdgcn_mfma_f32_32x32x16_bf16(
              __builtin_bit_cast(bf16x8, af4), __builtin_bit_cast(bf16x8, bfr), acc0, 0, 0, 0);
        }
        {
          const char* base = &hsb[1][0] + rowoff;
          u32x2 a0 = *(const u32x2*)(base + kk * 32 + hi * 16);
          u32x2 a1 = *(const u32x2*)(base + kk * 32 + hi * 16 + 8);
          u32x4 af4; af4[0] = a0[0]; af4[1] = a0[1]; af4[2] = a1[0]; af4[3] = a1[1];
          acc1 = __builtin_amdgcn_mfma_f32_32x32x16_bf16(
              __builtin_bit_cast(bf16x8, af4), __builtin_bit_cast(bf16x8, bfr), acc1, 0, 0, 0);
        }
      }
    }

    if (wv < 4) {                                // gathers: row = wv>>1, half = wv&1
      const int br = wv >> 1, hf = wv & 1;
      const uint32_t tgt = (uint32_t)(s + 1);
      const uint32_t* src = (br ? cm1 : cm0) + ((s + 1) & 1) * 1024;
      uint32_t g[8];
      for (;;) {
        uint32_t tsum = 0;
#pragma unroll
        for (int p = 0; p < 8; ++p) {
          g[p] = __hip_atomic_load(&src[p * 128 + hf * 64 + lane],
                                   __ATOMIC_RELAXED, __HIP_MEMORY_SCOPE_AGENT);
          tsum += g[p] & 0xffffu;
        }
        if (__all(tsum == 8u * tgt)) break;
        __builtin_amdgcn_s_sleep(1);
      }
      float v = 0.f;
#pragma unroll
      for (int p = 0; p < 8; ++p) v += bfhi(g[p]);
      vreg = v;
      float vn = __shfl_xor(v, 1);
      if (!(lane & 1)) htldp[br][hf * 32 + (lane >> 1)] = pkh(v, vn);
    }
    barrier_lgkm(); // bA

    // ===== P2: HT history stores + A-dot both rows =====
    if (slice == 0 && s > 0 && wv < 4) {
      int br = wv >> 1, hf = wv & 1;
      ws[OFF_HT + ((br ? b1 : b0) * 127 + (s - 1)) * DK + hf * 64 + lane] = vreg;
    }
#pragma unroll
    for (int rr = 0; rr < 2; ++rr) {
      float p0 = 0.f, p1 = 0.f, p2a = 0.f, p3a = 0.f;
#pragma unroll
      for (int t = 0; t < 8; ++t) {
        p0  = fdot2u(htldp[rr][akh * 32 + 4 * t + 0], Awh[4 * t + 0], p0);
        p1  = fdot2u(htldp[rr][akh * 32 + 4 * t + 1], Awh[4 * t + 1], p1);
        p2a = fdot2u(htldp[rr][akh * 32 + 4 * t + 2], Awh[4 * t + 2], p2a);
        p3a = fdot2u(htldp[rr][akh * 32 + 4 * t + 3], Awh[4 * t + 3], p3a);
      }
      float p = (p0 + p1) + (p2a + p3a);
      p += __shfl_xor(p, 1);                     // kh-sum
      float po = __shfl_xor(p, 2);               // m-exchange
      float v2 = am ? po : p;
      float v3 = am ? p : po;
      v2 += PST[rr][par][0][jA];
      v3 += PST[rr][par][1][jA];
      float lg = sigm(v3) * sigm(2.f * v2);      // sigmoid(v3)*(tanh(v2)+1)/2
      float lgn = __shfl_xor(lg, 4);             // partner jA+1
      if ((tid & 7) == 0) LGp[rr][tid >> 3] = pkh(lg, lgn);
    }
    barrier_lgkm(); // bB

    // ===== X: commit prefetch + {B-dot, gamma/update, pack, publish} per row =====
    if (tid >= 448) {
      qbuf[0][(s + 2) % 3][tid - 448] = qld[0];
      qbuf[1][(s + 2) % 3][tid - 448] = qld[1];
    }
    if (tid >= 128) {
      int mm = (tid - 128) >> 7, jj = tid & 127;
      PST[0][(s + 1) & 1][mm][jj] = pld[0];
      PST[1][(s + 1) & 1][mm][jj] = pld[1];
    }
#pragma unroll
    for (int rr = 0; rr < 2; ++rr) {
      float q0 = 0.f, q1 = 0.f, q2 = 0.f, q3 = 0.f;
#pragma unroll
      for (int t = 0; t < 8; ++t) {
        q0 = fdot2u(LGp[rr][hi * 32 + 4 * t + 0], W4Lh[hi * 32 + 4 * t + 0][jloc], q0);
        q1 = fdot2u(LGp[rr][hi * 32 + 4 * t + 1], W4Lh[hi * 32 + 4 * t + 1][jloc], q1);
        q2 = fdot2u(LGp[rr][hi * 32 + 4 * t + 2], W4Lh[hi * 32 + 4 * t + 2][jloc], q2);
        q3 = fdot2u(LGp[rr][hi * 32 + 4 * t + 3], W4Lh[hi * 32 + 4 * t + 3][jloc], q3);
      }
      float pB = (q0 + q1) + (q2 + q3);
      pB += __shfl_xor(pB, 32);
      float sb = PST[rr][par][2][jloc] + pB;
      float sn = sb * NLOG2E;
      f16x2 l2 = __builtin_bit_cast(f16x2, LGp[rr][jloc >> 1]);
      float lgj = (float)l2[jloc & 1];
      const float* qc = &qbuf[rr][s % 3][0];
      const float* qn = &qbuf[rr][(s + 1) % 3][0];
      f32x16 accr = rr ? acc1 : acc0;
      char* hb = &hsb[rr][0];
      float ht = 0.f;
#pragma unroll
      for (int q4 = 0; q4 < 4; ++q4) {
        int cbase = ct * 32 + 8 * q4 + 4 * hi;
        float4 qe4 = *(const float4*)&qc[cbase];
        float4 qn4 = *(const float4*)&qn[cbase];
#pragma unroll
        for (int rx = 0; rx < 4; ++rx) {
          int r = 4 * q4 + rx;
          float qe = (rx == 0) ? qe4.x : (rx == 1) ? qe4.y : (rx == 2) ? qe4.z : qe4.w;
          float qq = (rx == 0) ? qn4.x : (rx == 1) ? qn4.y : (rx == 2) ? qn4.z : qn4.w;
          int cl = cbase + rx;
          float g = v_rcp(1.0f + v_exp2(fmaf(accr[r], NLOG2E, sn)));
          float hn = fmaf(g, hm[rr][r], qe * lgj);
          hm[rr][r] = hn; ht = fmaf(qq, hn, ht);
          *(uint16_t*)(hb + cl * HROW + jloc * 2) = (uint16_t)pkbf(hn, 0.f);
        }
      }
      ht += __shfl_xor(ht, 32);
      uint32_t* cm = rr ? cm1 : cm0;
      if (hi == 0)                               // publish h_tilde(s+1) partial, tag s+2
        __hip_atomic_store(&cm[(s & 1) * 1024 + (slice * 2 + ct) * 128 + jloc],
                           pkbf(0.f, ht) | (uint32_t)(s + 2),
                           __ATOMIC_RELAXED, __HIP_MEMORY_SCOPE_AGENT);
    }
    barrier_lgkm(); // bD
  }

  // ---- tail: gather tag 128 (slot 0) -> HT row 126, both rows (slice 0, waves 0-3) ----
  if (slice == 0 && wv < 4) {
    const int br = wv >> 1, hf = wv & 1;
    const uint32_t* src = (br ? cm1 : cm0) + 0 * 1024;
    uint32_t g[8];
    for (;;) {
      uint32_t tsum = 0;
#pragma unroll
      for (int p = 0; p < 8; ++p) {
        g[p] = __hip_atomic_load(&src[p * 128 + hf * 64 + lane],
                                 __ATOMIC_RELAXED, __HIP_MEMORY_SCOPE_AGENT);
        tsum += g[p] & 0xffffu;
      }
      if (__all(tsum == 8u * 128u)) break;
      __builtin_amdgcn_s_sleep(1);
    }
    float v = 0.f;
#pragma unroll
    for (int p = 0; p < 8; ++p) v += bfhi(g[p]);
    ws[OFF_HT + ((br ? b1 : b0) * 127 + 126) * DK + hf * 64 + lane] = v;
  }
}

// ---------------- kernel 2: deferred y = mean_j sigmoid(preY + h_tilde @ W5h) ----------------
// Reads W5 directly (per-k coalesced over j; hts[u][k] is an LDS broadcast) - no kT needed.
__global__ __launch_bounds__(128) void k2_y(const float* __restrict__ ws,
                                            const float* __restrict__ W5,
                                            float* __restrict__ out)
{
  __shared__ float hts[8][128];
  __shared__ float part[2][8];
  int b = blockIdx.x >> 4, ch = blockIdx.x & 15, s0 = ch * 8;
  int j = threadIdx.x;
#pragma unroll
  for (int u = 0; u < 8; ++u) {
    int s = s0 + u;
    hts[u][j] = (s < 127) ? ws[OFF_HT + (b * 127 + s) * DK + j] : 0.f;
  }
  __syncthreads();
  float acc[8];
#pragma unroll
  for (int u = 0; u < 8; ++u) {
    int s = s0 + u;
    acc[u] = (s < 127) ? ws[OFF_PY + (b * 127 + s) * DK + j] : 0.f;
  }
#pragma unroll 4
  for (int k = 0; k < 128; ++k) {
    float w = W5[(128 + k) * DK + j];
#pragma unroll
    for (int u = 0; u < 8; ++u) acc[u] += w * hts[u][k];
  }
#pragma unroll
  for (int u = 0; u < 8; ++u) {
    float v = sigm(acc[u]);
#pragma unroll
    for (int off = 32; off >= 1; off >>= 1) v += __shfl_xor(v, off);
    if ((j & 63) == 0) part[j >> 6][u] = v;
  }
  __syncthreads();
  if (j < 8) {
    int s = s0 + j;
    if (s < 127) out[b * S + s + 1] = (part[0][j] + part[1][j]) * (1.0f / 128.0f);
  }
  if (j == 0 && ch == 0) out[b * S] = 0.f;
}

extern "C" void kernel_launch(void* const* d_in, const int* in_sizes, int n_in,
                              void* d_out, int out_size, void* d_ws, size_t ws_size,
                              hipStream_t stream)
{
  (void)in_sizes; (void)n_in; (void)out_size; (void)ws_size;
  const int*   e_data  = (const int*)  d_in[0];
  const int*   at_data = (const int*)  d_in[1];
  const int*   it_data = (const int*)  d_in[2];
  const float* a_data  = (const float*)d_in[3];
  const float* qmat    = (const float*)d_in[4];
  const float* e_E     = (const float*)d_in[5];
  const float* at_E    = (const float*)d_in[6];
  const float* it_E    = (const float*)d_in[7];
  const float* W1 = (const float*)d_in[8];  const float* b1 = (const float*)d_in[9];
  const float* W2 = (const float*)d_in[10]; const float* b2 = (const float*)d_in[11];
  const float* W3 = (const float*)d_in[12]; const float* b3 = (const float*)d_in[13];
  const float* W4 = (const float*)d_in[14]; const float* b4 = (const float*)d_in[15];
  const float* W5 = (const float*)d_in[16]; const float* b5 = (const float*)d_in[17];
  const float* h0 = (const float*)d_in[18];
  float* ws  = (float*)d_ws;
  float* out = (float*)d_out;

  // zero the tagged-comm region (tags must start != any step tag)
  hipMemsetAsync((char*)d_ws + (size_t)OFF_CM * 4, 0, (size_t)NB * 2 * 8 * 128 * 4, stream);

  k0_al <<<128, 512, 0, stream>>>(e_data, at_data, a_data, e_E, at_E, W1, b1, ws);
  k1_pre<<<128, 512, 0, stream>>>(e_data, it_data, it_E, e_E, W2, b2, W3, b3, W4, b4, W5, b5, ws);
  kmain <<<64, 512, 0, stream>>>(e_data, qmat, W2, W3, W4, h0, ws);
  k2_y  <<<512, 128, 0, stream>>>(ws, W5, out);
}

// Round 16
// 413.371 us; speedup vs baseline: 1.5199x; 1.5199x over previous
//
#include <hip/hip_runtime.h>
#include <stdint.h>

#define S   128
#define NB  32
#define NC  256
#define DK  128
#define NSL 4
#define HROW 264   // hsb row stride bytes: 264=8*33 -> bank stagger, 2-way max on b64

typedef __bf16 bf16x8 __attribute__((ext_vector_type(8)));
typedef float  f32x16 __attribute__((ext_vector_type(16)));
typedef unsigned int u32x4 __attribute__((ext_vector_type(4)));
typedef unsigned int u32x2 __attribute__((ext_vector_type(2)));
typedef _Float16 f16x2 __attribute__((ext_vector_type(2)));
static_assert(sizeof(bf16x8) == 16, "bf16x8 size");
static_assert(sizeof(f16x2) == 4, "f16x2 size");

// d_ws layout (float offsets).
#define OFF_AL   0            // AL; later OFF_HT (reduced h_tilde) reuse
#define OFF_HT   OFF_AL
#define OFF_P2   524288
#define OFF_P3   1044480
#define OFF_PS   1564672
#define OFF_PY   2084864
#define OFF_CM   2670592      // u32 comm [32 b][2 slot][8 pub][128 j] (memset 0 each launch)

__device__ __forceinline__ float v_exp2(float x){ float r; asm("v_exp_f32 %0, %1" : "=v"(r) : "v"(x)); return r; }
__device__ __forceinline__ float v_rcp (float x){ float r; asm("v_rcp_f32 %0, %1" : "=v"(r) : "v"(x)); return r; }
__device__ __forceinline__ float sigm(float x){ return v_rcp(1.0f + v_exp2(x * -1.4426950408889634f)); }
__device__ __forceinline__ uint32_t pkbf(float lo, float hi){
  uint32_t r; asm("v_cvt_pk_bf16_f32 %0, %1, %2" : "=v"(r) : "v"(lo), "v"(hi)); return r;
}
__device__ __forceinline__ float bfhi(uint32_t w){ return __builtin_bit_cast(float, w & 0xffff0000u); }
__device__ __forceinline__ uint32_t pkh(float a, float b){
  return __builtin_bit_cast(uint32_t, __builtin_amdgcn_cvt_pkrtz(a, b));
}
__device__ __forceinline__ float fdot2u(uint32_t a, uint32_t b, float c){
  return __builtin_amdgcn_fdot2(__builtin_bit_cast(f16x2, a), __builtin_bit_cast(f16x2, b), c, false);
}
// LDS-only barrier (no vmcnt drain): publish/HT stores and prefetch loads stay in flight.
__device__ __forceinline__ void barrier_lgkm(){
  asm volatile("s_waitcnt lgkmcnt(0)" ::: "memory");
  __builtin_amdgcn_s_barrier();
}
#define NLOG2E (-1.4426950408889634f)

// ---------------- kernel 0: AL = concat(e_emb, at_emb, a*ones50) @ W1 + b1 ----------------
__global__ __launch_bounds__(512) void k0_al(
    const int* __restrict__ e_data, const int* __restrict__ at_data,
    const float* __restrict__ a_data, const float* __restrict__ e_E,
    const float* __restrict__ at_E, const float* __restrict__ W1,
    const float* __restrict__ b1, float* __restrict__ ws)
{
  __shared__ float ein[32][128];
  __shared__ float atin[32][128];
  int b = blockIdx.x >> 2, q4 = blockIdx.x & 3, t0 = q4 * 32;
  for (int idx = threadIdx.x; idx < 32 * 128; idx += 512) {
    int r = idx >> 7, j = idx & 127;
    int ev  = e_data [b * S + t0 + r];
    int atv = at_data[b * S + t0 + r];
    ein [r][j] = e_E [ev  * DK + j];
    atin[r][j] = at_E[atv * DK + j];
  }
  __syncthreads();
  int j = threadIdx.x & 127, tq = threadIdx.x >> 7;
  float w1s = 0.f;
  for (int d = 0; d < 50; ++d) w1s += W1[(256 + d) * DK + j];
  float acc[8];
#pragma unroll
  for (int u = 0; u < 8; ++u) {
    int t = t0 + tq * 8 + u;
    acc[u] = b1[j] + a_data[b * S + t] * w1s;
  }
  for (int k = 0; k < 128; ++k) {
    float w = W1[k * DK + j];
#pragma unroll
    for (int u = 0; u < 8; ++u) acc[u] += ein[tq * 8 + u][k] * w;
  }
  for (int k = 0; k < 128; ++k) {
    float w = W1[(128 + k) * DK + j];
#pragma unroll
    for (int u = 0; u < 8; ++u) acc[u] += atin[tq * 8 + u][k] * w;
  }
#pragma unroll
  for (int u = 0; u < 8; ++u)
    ws[OFF_AL + (b * S + t0 + tq * 8 + u) * DK + j] = acc[u];
}

// ---------------- kernel 1: carry-independent per-step preactivations ----------------
__global__ __launch_bounds__(512) void k1_pre(
    const int* __restrict__ e_data, const int* __restrict__ it_data,
    const float* __restrict__ it_E, const float* __restrict__ e_E,
    const float* __restrict__ W2, const float* __restrict__ b2,
    const float* __restrict__ W3, const float* __restrict__ b3,
    const float* __restrict__ W4, const float* __restrict__ b4,
    const float* __restrict__ W5, const float* __restrict__ b5,
    float* __restrict__ ws)
{
  __shared__ float als[33][128];
  __shared__ float its[32][128];
  __shared__ float ens[32][128];
  int b = blockIdx.x >> 2, sh = blockIdx.x & 3, s0 = sh * 32;
  for (int idx = threadIdx.x; idx < 33 * 128; idx += 512) {
    int r = idx >> 7, j = idx & 127;
    int srow = s0 - 1 + r;
    als[r][j] = (srow >= 0) ? ws[OFF_AL + (b * S + srow) * DK + j] : 0.f;
  }
  for (int idx = threadIdx.x; idx < 32 * 128; idx += 512) {
    int r = idx >> 7, j = idx & 127;
    int itv = it_data[b * S + s0 + r];
    its[r][j] = it_E[itv * DK + j];
    int sg = s0 + r + 1; if (sg > 127) sg = 127;
    int ev = e_data[b * S + sg];
    ens[r][j] = e_E[ev * DK + j];
  }
  __syncthreads();
  int j = threadIdx.x & 127, sq = threadIdx.x >> 7;
  float p2[8], p3[8], pS[8], pY[8];
#pragma unroll
  for (int u = 0; u < 8; ++u) { p2[u] = b2[j]; p3[u] = b3[j]; pS[u] = b4[j]; pY[u] = b5[j]; }
  for (int k = 0; k < 128; ++k) {
    float w2 = W2[k * DK + j], w3 = W3[k * DK + j];
#pragma unroll
    for (int u = 0; u < 8; ++u) { float v = als[sq * 8 + u][k]; p2[u] += v * w2; p3[u] += v * w3; }
  }
  for (int k = 0; k < 128; ++k) {
    float w2 = W2[(128 + k) * DK + j], w3 = W3[(128 + k) * DK + j], w4 = W4[(256 + k) * DK + j];
#pragma unroll
    for (int u = 0; u < 8; ++u) { float v = its[sq * 8 + u][k]; p2[u] += v * w2; p3[u] += v * w3; pS[u] += v * w4; }
  }
  for (int k = 0; k < 128; ++k) {
    float w2 = W2[(256 + k) * DK + j], w3 = W3[(256 + k) * DK + j];
#pragma unroll
    for (int u = 0; u < 8; ++u) { float v = als[sq * 8 + u + 1][k]; p2[u] += v * w2; p3[u] += v * w3; }
  }
  for (int k = 0; k < 128; ++k) {
    float w5 = W5[k * DK + j];
#pragma unroll
    for (int u = 0; u < 8; ++u) pY[u] += ens[sq * 8 + u][k] * w5;
  }
#pragma unroll
  for (int u = 0; u < 8; ++u) {
    int s = s0 + sq * 8 + u;
    if (s < 127) {
      int o = (b * 127 + s) * DK + j;
      ws[OFF_P2 + o] = p2[u]; ws[OFF_P3 + o] = p3[u];
      ws[OFF_PS + o] = pS[u]; ws[OFF_PY + o] = pY[u];
    }
  }
}

// ---------------- main recurrent kernel: R13 structure + lgkm-only in-loop barriers ----------------
// (best measured: 330us kmain / 415us total). grid 128 = slice x b. Per step (3 barriers):
//  P1 [prefetch issue; MFMA; waves 0/1 gather own half (8 tagged u32, retry)] bA
//  P2 [HT store (slice0, wv<2, fire-and-forget); A-dot 4-acc fdot2 -> LGp] bB
//  X  [commit prefetch; B-dot 4-acc fdot2; gamma/h-update; hsb write; PUBLISH tag s+2] bD
// Publish(X end) and gather(P1 end) separated by barrier + prefetch + 8 MFMAs -> IC RT hidden.
__global__ __launch_bounds__(512, 2) void kmain(
    const int* __restrict__ e_data, const float* __restrict__ qmat,
    const float* __restrict__ W2, const float* __restrict__ W3,
    const float* __restrict__ W4, const float* __restrict__ h0,
    float* ws)
{
  __shared__ char     hsb[64 * HROW];     // h slice bf16, staggered rows (16.9KB)
  __shared__ u32x4    W4B[4][8][64];      // W4[0:128] MFMA B-frags per jt (32KB)
  __shared__ uint32_t W4Lh[64][128];      // W4[128:256] f16 pairs [k/2][j] (32KB)
  __shared__ float    qbuf[3][64];
  __shared__ float    PST[2][3][128];
  __shared__ uint32_t htldp[64];          // h_tilde as f16 pairs
  __shared__ uint32_t LGp[64];            // LG as f16 pairs

  const int bx = blockIdx.x;
  const int b = bx & 31, slice = bx >> 5;
  const int tid = threadIdx.x;
  const int lane = tid & 63, wv = tid >> 6;
  const int ct = wv >> 2, jt = wv & 3;
  const int lo = lane & 31, hi = lane >> 5;
  const int jA = tid >> 2, am = (tid >> 1) & 1, akh = tid & 1;
  const int jloc = jt * 32 + lo;

  uint32_t* cm32 = (uint32_t*)(ws + OFF_CM) + (size_t)b * 2048;   // [slot][pub8][128]

  // ---- persistent registers: Awh (32 f16-pairs) + hm (16) ----
  uint32_t Awh[32];
  {
    const float* Wm = am ? W3 : W2;
#pragma unroll
    for (int i = 0; i < 32; ++i) {
      float w0 = Wm[(384 + akh * 64 + 2 * i) * DK + jA];
      float w1 = Wm[(384 + akh * 64 + 2 * i + 1) * DK + jA];
      Awh[i] = pkh(w0, w1);
    }
  }
  float hm[16];
#pragma unroll
  for (int r = 0; r < 16; ++r) {
    int cl = ct * 32 + (r & 3) + 8 * (r >> 2) + 4 * hi;
    hm[r] = h0[(slice * 64 + cl) * DK + jloc];
  }

  // ---- prologue LDS fills ----
  {
    uint32_t* w4b = (uint32_t*)&W4B[0][0][0];
#pragma unroll
    for (int it = 0; it < 16; ++it) {            // MFMA B-frags (bf16 pairs, frag layout)
      int idx = tid + it * 512;
      int w = idx & 3, l = (idx >> 2) & 63, kk = (idx >> 8) & 7, jb = idx >> 11;
      int llo = l & 31, lhi = l >> 5;
      int row = kk * 16 + lhi * 8 + 2 * w, col = jb * 32 + llo;
      w4b[idx] = pkbf(W4[row * DK + col], W4[(row + 1) * DK + col]);
    }
  }
#pragma unroll
  for (int it = 0; it < 16; ++it) {              // W4Lh: f16 pairs of W4 rows 128..255
    int idx = tid + it * 512, kp = idx >> 7, jj = idx & 127;
    W4Lh[kp][jj] = pkh(W4[(128 + 2 * kp) * DK + jj], W4[(128 + 2 * kp + 1) * DK + jj]);
  }
  if (tid < 64) {
    qbuf[0][tid] = qmat[e_data[b * S + 0] * NC + slice * 64 + tid];
    qbuf[1][tid] = qmat[e_data[b * S + 1] * NC + slice * 64 + tid];
  }
  if (tid < 384) {
    int mm = tid >> 7, jj = tid & 127;
    int off = (mm == 0) ? OFF_P2 : (mm == 1) ? OFF_P3 : OFF_PS;
    PST[0][mm][jj] = ws[off + (b * 127 + 0) * DK + jj];
  }
#pragma unroll
  for (int r = 0; r < 16; ++r) {                 // pack h0 slice into hsb
    int cl = ct * 32 + (r & 3) + 8 * (r >> 2) + 4 * hi;
    *(uint16_t*)(hsb + cl * HROW + jloc * 2) = (uint16_t)pkbf(hm[r], 0.f);
  }
  __syncthreads();

  // ---- prologue: per-wave h_tilde(0) partial, publish tag 1 (slot 1) ----
  {
    float ht = 0.f;
#pragma unroll
    for (int r = 0; r < 16; ++r) {
      int cl = ct * 32 + (r & 3) + 8 * (r >> 2) + 4 * hi;
      ht += qbuf[0][cl] * hm[r];
    }
    ht += __shfl_xor(ht, 32);
    if (hi == 0)
      __hip_atomic_store(&cm32[1 * 1024 + (slice * 2 + ct) * 128 + jloc],
                         pkbf(0.f, ht) | 1u, __ATOMIC_RELAXED, __HIP_MEMORY_SCOPE_AGENT);
  }

  float vreg = 0.f;                              // waves 0/1: gathered f32 h_tilde half

#pragma unroll 1
  for (int s = 0; s < S - 1; ++s) {
    const int par = s & 1;

    // ===== P1: prefetch issue + MFMA + gather (waves 0/1) =====
    float qld = 0.f, pld = 0.f;
    if (tid >= 448)
      qld = qmat[e_data[b * S + min(s + 2, S - 1)] * NC + slice * 64 + (tid - 448)];
    if (tid >= 128) {
      int mm = (tid - 128) >> 7, jj = tid & 127;
      int off = (mm == 0) ? OFF_P2 : (mm == 1) ? OFF_P3 : OFF_PS;
      pld = ws[off + (b * 127 + min(s + 1, 126)) * DK + jj];
    }

    f32x16 acc;
#pragma unroll
    for (int r = 0; r < 16; ++r) acc[r] = 0.f;
    {
      const char* base = hsb + (ct * 32 + lo) * HROW;
#pragma unroll
      for (int kk = 0; kk < 8; ++kk) {
        u32x2 a0 = *(const u32x2*)(base + kk * 32 + hi * 16);
        u32x2 a1 = *(const u32x2*)(base + kk * 32 + hi * 16 + 8);
        u32x4 af4; af4[0] = a0[0]; af4[1] = a0[1]; af4[2] = a1[0]; af4[3] = a1[1];
        u32x4 bfr = W4B[jt][kk][lane];
        acc = __builtin_amdgcn_mfma_f32_32x32x16_bf16(
            __builtin_bit_cast(bf16x8, af4), __builtin_bit_cast(bf16x8, bfr), acc, 0, 0, 0);
      }
    }

    if (wv < 2) {                                // gather tag s+1 (slot (s+1)&1), own half
      const uint32_t tgt = (uint32_t)(s + 1);
      const uint32_t* src = cm32 + ((s + 1) & 1) * 1024;
      uint32_t g[8];
      for (;;) {
        uint32_t tsum = 0;
#pragma unroll
        for (int p = 0; p < 8; ++p) {
          g[p] = __hip_atomic_load(&src[p * 128 + wv * 64 + lane],
                                   __ATOMIC_RELAXED, __HIP_MEMORY_SCOPE_AGENT);
          tsum += g[p] & 0xffffu;
        }
        if (__all(tsum == 8u * tgt)) break;
        __builtin_amdgcn_s_sleep(1);
      }
      float v = 0.f;
#pragma unroll
      for (int p = 0; p < 8; ++p) v += bfhi(g[p]);
      vreg = v;
      float vn = __shfl_xor(v, 1);
      if (!(lane & 1)) htldp[wv * 32 + (lane >> 1)] = pkh(v, vn);
    }
    barrier_lgkm(); // bA

    // ===== P2: HT history store (fire-and-forget) + A-dot (4-acc fdot2) -> LGp =====
    if (slice == 0 && s > 0 && wv < 2)
      ws[OFF_HT + (b * 127 + (s - 1)) * DK + wv * 64 + lane] = vreg;
    {
      float p0 = 0.f, p1 = 0.f, p2a = 0.f, p3a = 0.f;
#pragma unroll
      for (int t = 0; t < 8; ++t) {
        p0  = fdot2u(htldp[akh * 32 + 4 * t + 0], Awh[4 * t + 0], p0);
        p1  = fdot2u(htldp[akh * 32 + 4 * t + 1], Awh[4 * t + 1], p1);
        p2a = fdot2u(htldp[akh * 32 + 4 * t + 2], Awh[4 * t + 2], p2a);
        p3a = fdot2u(htldp[akh * 32 + 4 * t + 3], Awh[4 * t + 3], p3a);
      }
      float p = (p0 + p1) + (p2a + p3a);
      p += __shfl_xor(p, 1);                     // kh-sum
      float po = __shfl_xor(p, 2);               // m-exchange
      float v2 = am ? po : p;
      float v3 = am ? p : po;
      v2 += PST[par][0][jA];
      v3 += PST[par][1][jA];
      float lg = sigm(v3) * sigm(2.f * v2);      // sigmoid(v3)*(tanh(v2)+1)/2
      float lgn = __shfl_xor(lg, 4);             // partner jA+1
      if ((tid & 7) == 0) LGp[tid >> 3] = pkh(lg, lgn);
    }
    barrier_lgkm(); // bB

    // ===== X: commit prefetch + B-dot (4-acc fdot2) + gamma/update/pack + publish =====
    if (tid >= 448) qbuf[(s + 2) % 3][tid - 448] = qld;
    if (tid >= 128) {
      int mm = (tid - 128) >> 7, jj = tid & 127;
      PST[(s + 1) & 1][mm][jj] = pld;
    }
    {
      float q0 = 0.f, q1 = 0.f, q2 = 0.f, q3 = 0.f;
#pragma unroll
      for (int t = 0; t < 8; ++t) {
        q0 = fdot2u(LGp[hi * 32 + 4 * t + 0], W4Lh[hi * 32 + 4 * t + 0][jloc], q0);
        q1 = fdot2u(LGp[hi * 32 + 4 * t + 1], W4Lh[hi * 32 + 4 * t + 1][jloc], q1);
        q2 = fdot2u(LGp[hi * 32 + 4 * t + 2], W4Lh[hi * 32 + 4 * t + 2][jloc], q2);
        q3 = fdot2u(LGp[hi * 32 + 4 * t + 3], W4Lh[hi * 32 + 4 * t + 3][jloc], q3);
      }
      float pB = (q0 + q1) + (q2 + q3);
      pB += __shfl_xor(pB, 32);
      float sb = PST[par][2][jloc] + pB;
      float sn = sb * NLOG2E;
      f16x2 l2 = __builtin_bit_cast(f16x2, LGp[jloc >> 1]);
      float lgj = (float)l2[jloc & 1];
      const float* qc = &qbuf[s % 3][0];
      const float* qn = &qbuf[(s + 1) % 3][0];
      float ht = 0.f;
#pragma unroll
      for (int q4 = 0; q4 < 4; ++q4) {
        int cbase = ct * 32 + 8 * q4 + 4 * hi;
        float4 qe4 = *(const float4*)&qc[cbase];
        float4 qn4 = *(const float4*)&qn[cbase];
#pragma unroll
        for (int rr = 0; rr < 4; ++rr) {
          int r = 4 * q4 + rr;
          float qe = (rr == 0) ? qe4.x : (rr == 1) ? qe4.y : (rr == 2) ? qe4.z : qe4.w;
          float qq = (rr == 0) ? qn4.x : (rr == 1) ? qn4.y : (rr == 2) ? qn4.z : qn4.w;
          int cl = cbase + rr;
          float g = v_rcp(1.0f + v_exp2(fmaf(acc[r], NLOG2E, sn)));
          float hn = fmaf(g, hm[r], qe * lgj);
          hm[r] = hn; ht = fmaf(qq, hn, ht);
          *(uint16_t*)(hsb + cl * HROW + jloc * 2) = (uint16_t)pkbf(hn, 0.f);
        }
      }
      ht += __shfl_xor(ht, 32);
      if (hi == 0)                               // publish h_tilde(s+1) partial, tag s+2
        __hip_atomic_store(&cm32[(s & 1) * 1024 + (slice * 2 + ct) * 128 + jloc],
                           pkbf(0.f, ht) | (uint32_t)(s + 2),
                           __ATOMIC_RELAXED, __HIP_MEMORY_SCOPE_AGENT);
    }
    barrier_lgkm(); // bD
  }

  // ---- tail: gather tag 128 (slot 0) -> HT row 126 (slice 0, waves 0/1) ----
  if (slice == 0 && wv < 2) {
    const uint32_t* src = cm32 + 0 * 1024;
    uint32_t g[8];
    for (;;) {
      uint32_t tsum = 0;
#pragma unroll
      for (int p = 0; p < 8; ++p) {
        g[p] = __hip_atomic_load(&src[p * 128 + wv * 64 + lane],
                                 __ATOMIC_RELAXED, __HIP_MEMORY_SCOPE_AGENT);
        tsum += g[p] & 0xffffu;
      }
      if (__all(tsum == 8u * 128u)) break;
      __builtin_amdgcn_s_sleep(1);
    }
    float v = 0.f;
#pragma unroll
    for (int p = 0; p < 8; ++p) v += bfhi(g[p]);
    ws[OFF_HT + (b * 127 + 126) * DK + wv * 64 + lane] = v;
  }
}

// ---------------- kernel 2: deferred y = mean_j sigmoid(preY + h_tilde @ W5h) ----------------
// Reads W5 directly (per-k coalesced over j; hts[u][k] is an LDS broadcast) - no kT needed.
__global__ __launch_bounds__(128) void k2_y(const float* __restrict__ ws,
                                            const float* __restrict__ W5,
                                            float* __restrict__ out)
{
  __shared__ float hts[8][128];
  __shared__ float part[2][8];
  int b = blockIdx.x >> 4, ch = blockIdx.x & 15, s0 = ch * 8;
  int j = threadIdx.x;
#pragma unroll
  for (int u = 0; u < 8; ++u) {
    int s = s0 + u;
    hts[u][j] = (s < 127) ? ws[OFF_HT + (b * 127 + s) * DK + j] : 0.f;
  }
  __syncthreads();
  float acc[8];
#pragma unroll
  for (int u = 0; u < 8; ++u) {
    int s = s0 + u;
    acc[u] = (s < 127) ? ws[OFF_PY + (b * 127 + s) * DK + j] : 0.f;
  }
#pragma unroll 4
  for (int k = 0; k < 128; ++k) {
    float w = W5[(128 + k) * DK + j];
#pragma unroll
    for (int u = 0; u < 8; ++u) acc[u] += w * hts[u][k];
  }
#pragma unroll
  for (int u = 0; u < 8; ++u) {
    float v = sigm(acc[u]);
#pragma unroll
    for (int off = 32; off >= 1; off >>= 1) v += __shfl_xor(v, off);
    if ((j & 63) == 0) part[j >> 6][u] = v;
  }
  __syncthreads();
  if (j < 8) {
    int s = s0 + j;
    if (s < 127) out[b * S + s + 1] = (part[0][j] + part[1][j]) * (1.0f / 128.0f);
  }
  if (j == 0 && ch == 0) out[b * S] = 0.f;
}

extern "C" void kernel_launch(void* const* d_in, const int* in_sizes, int n_in,
                              void* d_out, int out_size, void* d_ws, size_t ws_size,
                              hipStream_t stream)
{
  (void)in_sizes; (void)n_in; (void)out_size; (void)ws_size;
  const int*   e_data  = (const int*)  d_in[0];
  const int*   at_data = (const int*)  d_in[1];
  const int*   it_data = (const int*)  d_in[2];
  const float* a_data  = (const float*)d_in[3];
  const float* qmat    = (const float*)d_in[4];
  const float* e_E     = (const float*)d_in[5];
  const float* at_E    = (const float*)d_in[6];
  const float* it_E    = (const float*)d_in[7];
  const float* W1 = (const float*)d_in[8];  const float* b1 = (const float*)d_in[9];
  const float* W2 = (const float*)d_in[10]; const float* b2 = (const float*)d_in[11];
  const float* W3 = (const float*)d_in[12]; const float* b3 = (const float*)d_in[13];
  const float* W4 = (const float*)d_in[14]; const float* b4 = (const float*)d_in[15];
  const float* W5 = (const float*)d_in[16]; const float* b5 = (const float*)d_in[17];
  const float* h0 = (const float*)d_in[18];
  float* ws  = (float*)d_ws;
  float* out = (float*)d_out;

  // zero the tagged-comm region (tags must start != any step tag)
  hipMemsetAsync((char*)d_ws + (size_t)OFF_CM * 4, 0, (size_t)NB * 2 * 8 * 128 * 4, stream);

  k0_al <<<128, 512, 0, stream>>>(e_data, at_data, a_data, e_E, at_E, W1, b1, ws);
  k1_pre<<<128, 512, 0, stream>>>(e_data, it_data, it_E, e_E, W2, b2, W3, b3, W4, b4, W5, b5, ws);
  kmain <<<128, 512, 0, stream>>>(e_data, qmat, W2, W3, W4, h0, ws);
  k2_y  <<<512, 128, 0, stream>>>(ws, W5, out);
}